// Round 4
// baseline (411.272 us; speedup 1.0000x reference)
//
#include <hip/hip_runtime.h>
#include <math.h>

constexpr int Bn = 16, SY = 2048, SX = 2048, Dd = 128;
constexpr int YT = 64;          // y rows per block (4 waves x 16)
constexpr int XT = 64;          // x cols per tile
constexpr int NXT = SX / XT;    // 32
constexpr int PIT = 72;         // pitch for 64-halfword rows: 144B = 9x16B

using half8  = __attribute__((ext_vector_type(8))) _Float16;
using half4  = __attribute__((ext_vector_type(4))) _Float16;
using floatx4 = __attribute__((ext_vector_type(4))) float;

// ws layout (fp16 element offsets): y16 @0, x16 @+8MiB, xT16 @+16MiB (24 MiB total)
constexpr size_t WS_X16  = (size_t)Bn * SY * Dd;
constexpr size_t WS_XT16 = 2 * WS_X16;

__global__ void zero_kernel(float* __restrict__ p, int n) {
  int i = blockIdx.x * 256 + threadIdx.x;
  if (i < n) p[i] = 0.f;
}

// y (fp32) -> y16 fp16 row-major
__global__ void cvt_y_kernel(const float* __restrict__ y, _Float16* __restrict__ y16) {
  size_t i = ((size_t)blockIdx.x * 256 + threadIdx.x) * 8;
  floatx4 f0 = *(const floatx4*)(y + i);
  floatx4 f1 = *(const floatx4*)(y + i + 4);
  half8 h;
  h[0]=(_Float16)f0[0]; h[1]=(_Float16)f0[1]; h[2]=(_Float16)f0[2]; h[3]=(_Float16)f0[3];
  h[4]=(_Float16)f1[0]; h[5]=(_Float16)f1[1]; h[6]=(_Float16)f1[2]; h[7]=(_Float16)f1[3];
  *(half8*)(y16 + i) = h;
}

// x (fp32) -> x16 (fp16 row-major) + xT16 (fp16 d-major [b][d][xrow]).
// grid 512 = 16 b x 32 row-blocks of 64 x-rows; 256 threads.
__global__ void xpose_kernel(const float* __restrict__ x,
                             _Float16* __restrict__ x16, _Float16* __restrict__ xT16) {
  __shared__ _Float16 lt[128 * PIT];   // [d][xrow(64)+pad], pitch 72
  const int t = threadIdx.x;
  const int b = blockIdx.x >> 5, rb = blockIdx.x & 31;
  const float* xp = x + ((size_t)b * SX + rb * 64) * Dd;
  _Float16* x16p = x16 + ((size_t)b * SX + rb * 64) * Dd;

  #pragma unroll
  for (int it = 0; it < 8; ++it) {           // 64 rows x 32 float4-cols
    int tau = it * 256 + t;
    int row = tau >> 5, c4 = tau & 31;
    floatx4 f = *(const floatx4*)(xp + row * Dd + 4 * c4);
    half4 h;
    h[0]=(_Float16)f[0]; h[1]=(_Float16)f[1]; h[2]=(_Float16)f[2]; h[3]=(_Float16)f[3];
    *(half4*)(x16p + row * Dd + 4 * c4) = h;
    #pragma unroll
    for (int j = 0; j < 4; ++j) lt[(4 * c4 + j) * PIT + row] = h[j];
  }
  __syncthreads();
  #pragma unroll
  for (int it = 0; it < 4; ++it) {           // 128 d-rows x 8 granules of 16B
    int tau = it * 256 + t;
    int d = tau >> 3, g = tau & 7;
    half8 h = *(const half8*)&lt[d * PIT + g * 8];
    *(half8*)(xT16 + (size_t)(b * Dd + d) * SX + rb * 64 + g * 8) = h;
  }
}

__device__ __forceinline__ float sel4(const float* a, int q) {
  float r = a[0];
  r = (q == 1) ? a[1] : r;
  r = (q == 2) ? a[2] : r;
  r = (q == 3) ? a[3] : r;
  return r;
}

// grid 512: b*32 + yblk(64 rows). 4 waves x 16 rows. Flash over 32 x-tiles of 64.
// No in-loop barriers: B-frags from global fp16 (L2-resident, 512KB/layout/batch),
// Pw is per-wave LDS, visual via per-wave coalesced atomics.
__launch_bounds__(256, 2)
__global__ void attn_kernel(const _Float16* __restrict__ x16, const _Float16* __restrict__ xT16,
                            const _Float16* __restrict__ y16,
                            float* __restrict__ visual, float* __restrict__ out) {
  __shared__ _Float16 Pw[4][16 * PIT];     // per-wave P [m][xcol], pitch 72
  __shared__ float obuf[4][128];

  const int t = threadIdx.x;
  const int w = t >> 6, lane = t & 63;
  const int n = lane & 15, q = lane >> 4;   // lane = 16q + n
  const int b = blockIdx.x >> 5;
  const int y0 = (blockIdx.x & 31) * YT;

  // ---- y A-frags (fp16, contiguous 16B, reused 32x) ----
  const _Float16* yr = y16 + ((size_t)(b * SY + y0 + w * 16 + n)) * Dd;
  half8 afrag[4];
  #pragma unroll
  for (int k = 0; k < 4; ++k) afrag[k] = *(const half8*)(yr + k * 32 + q * 8);

  float m_r[4], l_r[4];
  #pragma unroll
  for (int r = 0; r < 4; ++r) { m_r[r] = -INFINITY; l_r[r] = 0.f; }
  floatx4 acc_o[8];
  #pragma unroll
  for (int d = 0; d < 8; ++d) acc_o[d] = (floatx4){0.f, 0.f, 0.f, 0.f};

  const _Float16* xb  = x16  + (size_t)b * SX * Dd;   // [xrow][d]
  const _Float16* xTb = xT16 + (size_t)b * Dd * SX;   // [d][xrow]
  constexpr float inv_n = 1.0f / 2048.0f;

  for (int xt = 0; xt < NXT; ++xt) {
    // ---- S = y @ x^T (16x64 per wave), B-frags from global x16 ----
    const _Float16* xtile = xb + (size_t)xt * XT * Dd;
    floatx4 acc_s[4];
    #pragma unroll
    for (int c = 0; c < 4; ++c) acc_s[c] = (floatx4){0.f, 0.f, 0.f, 0.f};
    #pragma unroll
    for (int k = 0; k < 4; ++k) {
      half8 bf[4];
      #pragma unroll
      for (int c = 0; c < 4; ++c)
        bf[c] = *(const half8*)(xtile + (16 * c + n) * Dd + k * 32 + q * 8);
      #pragma unroll
      for (int c = 0; c < 4; ++c)
        acc_s[c] = __builtin_amdgcn_mfma_f32_16x16x32_f16(afrag[k], bf[c], acc_s[c], 0, 0, 0);
    }

    // ---- visual: raw-score col sums; lane = column -> coalesced atomic ----
    {
      float cs4[4];
      #pragma unroll
      for (int c = 0; c < 4; ++c) {
        float cs = acc_s[c][0] + acc_s[c][1] + acc_s[c][2] + acc_s[c][3];
        cs += __shfl_xor(cs, 16);
        cs += __shfl_xor(cs, 32);
        cs4[c] = cs;   // full 16-row sum for col 16c+n, replicated per quad
      }
      atomicAdd(visual + (size_t)b * SX + xt * XT + lane, sel4(cs4, q) * inv_n);
    }

    // ---- online softmax (all intra-quad) ----
    float mt[4], alpha[4];
    #pragma unroll
    for (int r = 0; r < 4; ++r) {
      float mv = fmaxf(fmaxf(acc_s[0][r], acc_s[1][r]), fmaxf(acc_s[2][r], acc_s[3][r]));
      mv = fmaxf(mv, __shfl_xor(mv, 1));
      mv = fmaxf(mv, __shfl_xor(mv, 2));
      mv = fmaxf(mv, __shfl_xor(mv, 4));
      mv = fmaxf(mv, __shfl_xor(mv, 8));
      mt[r] = fmaxf(m_r[r], mv);
      alpha[r] = __expf(m_r[r] - mt[r]);   // 0 on first tile
      m_r[r] = mt[r];
    }
    #pragma unroll
    for (int r = 0; r < 4; ++r) {
      float rs = 0.f;
      #pragma unroll
      for (int c = 0; c < 4; ++c) {
        float e = __expf(acc_s[c][r] - mt[r]);
        rs += e;
        Pw[w][(4 * q + r) * PIT + 16 * c + n] = (_Float16)e;
      }
      rs += __shfl_xor(rs, 1);
      rs += __shfl_xor(rs, 2);
      rs += __shfl_xor(rs, 4);
      rs += __shfl_xor(rs, 8);
      l_r[r] = l_r[r] * alpha[r] + rs;
      #pragma unroll
      for (int d = 0; d < 8; ++d) acc_o[d][r] *= alpha[r];
    }

    // ---- O += P @ x : A from own Pw (same-wave RAW, compiler waits),
    //      B from global xT16 ----
    #pragma unroll
    for (int k2 = 0; k2 < 2; ++k2) {
      half8 pf = *(const half8*)&Pw[w][n * PIT + k2 * 32 + q * 8];
      #pragma unroll
      for (int d = 0; d < 8; ++d) {
        half8 xf = *(const half8*)(xTb + (size_t)(16 * d + n) * SX + xt * XT + k2 * 32 + q * 8);
        acc_o[d] = __builtin_amdgcn_mfma_f32_16x16x32_f16(pf, xf, acc_o[d], 0, 0, 0);
      }
    }
  }

  // ---- epilogue: out[b][d] = mean_y O[y][d]/l[y] ----
  float inv_l[4];
  #pragma unroll
  for (int r = 0; r < 4; ++r) inv_l[r] = 1.f / l_r[r];
  float ps[8];
  #pragma unroll
  for (int d = 0; d < 8; ++d) {
    float s = acc_o[d][0] * inv_l[0] + acc_o[d][1] * inv_l[1] +
              acc_o[d][2] * inv_l[2] + acc_o[d][3] * inv_l[3];
    s += __shfl_xor(s, 16);
    s += __shfl_xor(s, 32);
    ps[d] = s;   // 16-row sum for col 16d+n, replicated
  }
  obuf[w][16 * q + n]       = sel4(ps, q);       // d 0..63
  obuf[w][16 * (q + 4) + n] = sel4(ps + 4, q);   // d 64..127
  __syncthreads();
  if (t < 128) {
    float s = obuf[0][t] + obuf[1][t] + obuf[2][t] + obuf[3][t];
    atomicAdd(out + (size_t)b * Dd + t, s * inv_n);
  }
}

extern "C" void kernel_launch(void* const* d_in, const int* in_sizes, int n_in,
                              void* d_out, int out_size, void* d_ws, size_t ws_size,
                              hipStream_t stream) {
  const float* x = (const float*)d_in[0];   // [B, SX, D]
  const float* y = (const float*)d_in[1];   // [B, SY, D]
  float* visual = (float*)d_out;                      // [B, SX]
  float* out    = (float*)d_out + (size_t)Bn * SX;    // [B, D]

  _Float16* y16  = (_Float16*)d_ws;
  _Float16* x16  = (_Float16*)d_ws + WS_X16;
  _Float16* xT16 = (_Float16*)d_ws + WS_XT16;

  int ntot = Bn * SX + Bn * Dd;
  zero_kernel<<<(ntot + 255) / 256, 256, 0, stream>>>((float*)d_out, ntot);
  cvt_y_kernel<<<(Bn * SY * Dd) / (8 * 256), 256, 0, stream>>>(y, y16);
  xpose_kernel<<<Bn * (SX / 64), 256, 0, stream>>>(x, x16, xT16);
  attn_kernel<<<Bn * (SY / YT), 256, 0, stream>>>(x16, xT16, y16, visual, out);
}

// Round 5
// 341.098 us; speedup vs baseline: 1.2057x; 1.2057x over previous
//
#include <hip/hip_runtime.h>
#include <math.h>

constexpr int Bn = 16, SY = 2048, SX = 2048, Dd = 128;
constexpr int XT = 64;
constexpr int PIT = 72;   // halfword pitch: 144B = 9x16B, conflict-balanced
constexpr float INV_N = 1.0f / 2048.0f;
constexpr size_t NE = (size_t)Bn * SY * Dd;   // 4,194,304 elements

using half8  = __attribute__((ext_vector_type(8))) _Float16;
using half4  = __attribute__((ext_vector_type(4))) _Float16;
using floatx4 = __attribute__((ext_vector_type(4))) float;

#define DPP_ROR(v, ctrl) __int_as_float(__builtin_amdgcn_update_dpp( \
    __float_as_int(v), __float_as_int(v), (ctrl), 0xf, 0xf, false))

__device__ __forceinline__ float rowmax16(float v) {
  // max over the 16-lane DPP row (lanes sharing q) via rotate-right reduce
  v = fmaxf(v, DPP_ROR(v, 0x121));   // ror 1
  v = fmaxf(v, DPP_ROR(v, 0x122));   // ror 2
  v = fmaxf(v, DPP_ROR(v, 0x124));   // ror 4
  v = fmaxf(v, DPP_ROR(v, 0x128));   // ror 8
  return v;
}

__device__ __forceinline__ float sel4(const float* a, int q) {
  float r = a[0];
  r = (q == 1) ? a[1] : r;
  r = (q == 2) ? a[2] : r;
  r = (q == 3) ? a[3] : r;
  return r;
}

// grid 512, 256 thr. Block blk: (b=blk>>5, rb=blk&31) x-transpose tile of 64 rows,
// plus 8192 contiguous y elements converted + column-partial-summed (ysump).
__global__ void prep_kernel(const float* __restrict__ x, const float* __restrict__ y,
                            _Float16* __restrict__ x16, _Float16* __restrict__ xT16,
                            _Float16* __restrict__ y16, float* __restrict__ ysump) {
  __shared__ _Float16 lt[128 * PIT];
  __shared__ float psum[16][128];
  const int t = threadIdx.x, blk = blockIdx.x;
  const int b = blk >> 5, rb = blk & 31;

  // ---- x: convert + build transposed tile in LDS ----
  const float* xp = x + ((size_t)b * SX + rb * 64) * Dd;
  _Float16* x16p = x16 + ((size_t)b * SX + rb * 64) * Dd;
  #pragma unroll
  for (int it = 0; it < 8; ++it) {           // 64 rows x 32 float4-cols
    int tau = it * 256 + t;
    int row = tau >> 5, c4 = tau & 31;
    floatx4 f = *(const floatx4*)(xp + row * Dd + 4 * c4);
    half4 h;
    h[0]=(_Float16)f[0]; h[1]=(_Float16)f[1]; h[2]=(_Float16)f[2]; h[3]=(_Float16)f[3];
    *(half4*)(x16p + row * Dd + 4 * c4) = h;
    #pragma unroll
    for (int j = 0; j < 4; ++j) lt[(4 * c4 + j) * PIT + row] = h[j];
  }

  // ---- y: convert 8192 contiguous elems + column partial sums (fp32) ----
  const float* ysrc = y + (size_t)blk * 8192;
  _Float16* ydst = y16 + (size_t)blk * 8192;
  float cp[8];
  #pragma unroll
  for (int j = 0; j < 8; ++j) cp[j] = 0.f;
  #pragma unroll
  for (int it = 0; it < 4; ++it) {
    int idx = (it * 256 + t) * 8;
    floatx4 f0 = *(const floatx4*)(ysrc + idx);
    floatx4 f1 = *(const floatx4*)(ysrc + idx + 4);
    half8 h;
    h[0]=(_Float16)f0[0]; h[1]=(_Float16)f0[1]; h[2]=(_Float16)f0[2]; h[3]=(_Float16)f0[3];
    h[4]=(_Float16)f1[0]; h[5]=(_Float16)f1[1]; h[6]=(_Float16)f1[2]; h[7]=(_Float16)f1[3];
    *(half8*)(ydst + idx) = h;
    cp[0]+=f0[0]; cp[1]+=f0[1]; cp[2]+=f0[2]; cp[3]+=f0[3];
    cp[4]+=f1[0]; cp[5]+=f1[1]; cp[6]+=f1[2]; cp[7]+=f1[3];
  }
  {
    int rr = t >> 4, cc = (t & 15) * 8;   // thread t's 8 cols are (t&15)*8 + j
    *(floatx4*)&psum[rr][cc]     = (floatx4){cp[0], cp[1], cp[2], cp[3]};
    *(floatx4*)&psum[rr][cc + 4] = (floatx4){cp[4], cp[5], cp[6], cp[7]};
  }
  __syncthreads();

  // ---- xT16 writeout ----
  #pragma unroll
  for (int it = 0; it < 4; ++it) {           // 128 d-rows x 8 granules of 16B
    int tau = it * 256 + t;
    int d = tau >> 3, g = tau & 7;
    half8 h = *(const half8*)&lt[d * PIT + g * 8];
    *(half8*)(xT16 + (size_t)(b * Dd + d) * SX + rb * 64 + g * 8) = h;
  }
  // ---- ysump writeout ----
  if (t < 128) {
    float s = 0.f;
    #pragma unroll
    for (int i = 0; i < 16; ++i) s += psum[i][t];
    ysump[(size_t)blk * 128 + t] = s;
  }
}

// grid 512 (XCD-swizzled), 256 thr = 4 waves x 16 y-rows. Each wave runs TWO
// independent flash streams (x-tiles it and it+16), combined in-register at the
// end. l via MFMA-with-ones; row max via DPP; no atomics, no barriers.
__launch_bounds__(256, 2)
__global__ void attn_kernel(const _Float16* __restrict__ x16, const _Float16* __restrict__ xT16,
                            const _Float16* __restrict__ y16, float* __restrict__ out_ws) {
  __shared__ _Float16 Pw[8][16 * PIT];   // [wave*2+stream][m][xcol]

  const int t = threadIdx.x;
  const int w = t >> 6, lane = t & 63;
  const int n = lane & 15, q = lane >> 4;
  const int xcd = blockIdx.x & 7, kk = blockIdx.x >> 3;
  const int b = (xcd << 1) | (kk & 1);   // pin each b's 2MB working set to one XCD
  const int yblk = kk >> 1;
  const int y0 = yblk * 64;

  const _Float16* yr = y16 + ((size_t)(b * SY + y0 + w * 16 + n)) * Dd;
  half8 afrag[4];
  #pragma unroll
  for (int k = 0; k < 4; ++k) afrag[k] = *(const half8*)(yr + k * 32 + q * 8);

  half8 ones;
  #pragma unroll
  for (int j = 0; j < 8; ++j) ones[j] = (_Float16)1.0f;

  float mA[4], mB[4];
  floatx4 oA[8], oB[8], lA, lB;
  #pragma unroll
  for (int r = 0; r < 4; ++r) { mA[r] = -INFINITY; mB[r] = -INFINITY; }
  #pragma unroll
  for (int d = 0; d < 8; ++d) { oA[d] = (floatx4){0,0,0,0}; oB[d] = (floatx4){0,0,0,0}; }
  lA = (floatx4){0,0,0,0}; lB = (floatx4){0,0,0,0};

  const _Float16* xb  = x16  + (size_t)b * SX * Dd;
  const _Float16* xTb = xT16 + (size_t)b * Dd * SX;
  _Float16* PA = Pw[w * 2 + 0];
  _Float16* PB = Pw[w * 2 + 1];

  for (int it = 0; it < 16; ++it) {
    const _Float16* xtA = xb + (size_t)it * XT * Dd;
    const _Float16* xtB = xb + (size_t)(it + 16) * XT * Dd;

    // ---- S for both streams ----
    floatx4 sA[4], sB[4];
    #pragma unroll
    for (int c = 0; c < 4; ++c) { sA[c] = (floatx4){0,0,0,0}; sB[c] = (floatx4){0,0,0,0}; }
    #pragma unroll
    for (int k = 0; k < 4; ++k) {
      half8 bA[4], bB[4];
      #pragma unroll
      for (int c = 0; c < 4; ++c) bA[c] = *(const half8*)(xtA + (16 * c + n) * Dd + k * 32 + q * 8);
      #pragma unroll
      for (int c = 0; c < 4; ++c) bB[c] = *(const half8*)(xtB + (16 * c + n) * Dd + k * 32 + q * 8);
      #pragma unroll
      for (int c = 0; c < 4; ++c) sA[c] = __builtin_amdgcn_mfma_f32_16x16x32_f16(afrag[k], bA[c], sA[c], 0, 0, 0);
      #pragma unroll
      for (int c = 0; c < 4; ++c) sB[c] = __builtin_amdgcn_mfma_f32_16x16x32_f16(afrag[k], bB[c], sB[c], 0, 0, 0);
    }

    // ---- online softmax, both streams (max via DPP, no DS) ----
    float mtA[4], mtB[4], aA[4], aB[4];
    #pragma unroll
    for (int r = 0; r < 4; ++r) {
      float vA = fmaxf(fmaxf(sA[0][r], sA[1][r]), fmaxf(sA[2][r], sA[3][r]));
      float vB = fmaxf(fmaxf(sB[0][r], sB[1][r]), fmaxf(sB[2][r], sB[3][r]));
      vA = rowmax16(vA);  vB = rowmax16(vB);
      mtA[r] = fmaxf(mA[r], vA);  mtB[r] = fmaxf(mB[r], vB);
      aA[r] = __expf(mA[r] - mtA[r]);  aB[r] = __expf(mB[r] - mtB[r]);
      mA[r] = mtA[r];  mB[r] = mtB[r];
    }
    #pragma unroll
    for (int r = 0; r < 4; ++r) {
      #pragma unroll
      for (int c = 0; c < 4; ++c) {
        PA[(4 * q + r) * PIT + 16 * c + n] = (_Float16)__expf(sA[c][r] - mtA[r]);
        PB[(4 * q + r) * PIT + 16 * c + n] = (_Float16)__expf(sB[c][r] - mtB[r]);
      }
      lA[r] *= aA[r];  lB[r] *= aB[r];
      #pragma unroll
      for (int d = 0; d < 8; ++d) { oA[d][r] *= aA[r]; oB[d][r] *= aB[r]; }
    }

    // ---- PV + l (MFMA with ones). Same-wave LDS RAW; no barrier. ----
    const _Float16* xTA = xTb + it * XT;
    const _Float16* xTB = xTb + (it + 16) * XT;
    #pragma unroll
    for (int k2 = 0; k2 < 2; ++k2) {
      half8 pA = *(const half8*)&PA[n * PIT + k2 * 32 + q * 8];
      half8 pB = *(const half8*)&PB[n * PIT + k2 * 32 + q * 8];
      lA = __builtin_amdgcn_mfma_f32_16x16x32_f16(pA, ones, lA, 0, 0, 0);
      lB = __builtin_amdgcn_mfma_f32_16x16x32_f16(pB, ones, lB, 0, 0, 0);
      #pragma unroll
      for (int d = 0; d < 8; ++d) {
        half8 xfA = *(const half8*)(xTA + (size_t)(16 * d + n) * SX + k2 * 32 + q * 8);
        oA[d] = __builtin_amdgcn_mfma_f32_16x16x32_f16(pA, xfA, oA[d], 0, 0, 0);
      }
      #pragma unroll
      for (int d = 0; d < 8; ++d) {
        half8 xfB = *(const half8*)(xTB + (size_t)(16 * d + n) * SX + k2 * 32 + q * 8);
        oB[d] = __builtin_amdgcn_mfma_f32_16x16x32_f16(pB, xfB, oB[d], 0, 0, 0);
      }
    }
  }

  // ---- epilogue: combine streams in-register, write per-wave out partial ----
  float scA[4], scB[4], inv_l[4];
  #pragma unroll
  for (int r = 0; r < 4; ++r) {
    float ms = fmaxf(mA[r], mB[r]);
    scA[r] = __expf(mA[r] - ms);
    scB[r] = __expf(mB[r] - ms);
    float l = scA[r] * lA[r] + scB[r] * lB[r];
    inv_l[r] = 1.f / l;
  }
  float ps[8];
  #pragma unroll
  for (int d = 0; d < 8; ++d) {
    float s = 0.f;
    #pragma unroll
    for (int r = 0; r < 4; ++r)
      s += (scA[r] * oA[d][r] + scB[r] * oB[d][r]) * inv_l[r];
    s += __shfl_xor(s, 16);
    s += __shfl_xor(s, 32);
    ps[d] = s;   // 16-row sum for col 16d+n, replicated
  }
  float* wb = out_ws + ((size_t)(b * 32 + yblk) * 4 + w) * 128;
  wb[16 * q + n]      = sel4(ps, q);
  wb[64 + 16 * q + n] = sel4(ps + 4, q);
}

// grid 129, 256 thr. Blocks 0..127: visual[b, x0..x0+255] = (ysum . x)/2048.
// Block 128: out[b][d] = mean over 128 wave-partials.
__global__ void finale_kernel(const _Float16* __restrict__ x16, const float* __restrict__ ysump,
                              const float* __restrict__ out_ws,
                              float* __restrict__ visual, float* __restrict__ out) {
  const int t = threadIdx.x, blk = blockIdx.x;
  if (blk < 128) {
    __shared__ float ysum[128];
    const int b = blk >> 3, x0 = (blk & 7) * 256;
    if (t < 128) {
      float s = 0.f;
      #pragma unroll
      for (int j = 0; j < 32; ++j) s += ysump[(size_t)(b * 32 + j) * 128 + t];
      ysum[t] = s;
    }
    __syncthreads();
    const int x = x0 + t;
    const _Float16* xr = x16 + ((size_t)b * SX + x) * Dd;
    float dot = 0.f;
    #pragma unroll
    for (int g = 0; g < 16; ++g) {
      half8 h = *(const half8*)(xr + g * 8);
      #pragma unroll
      for (int j = 0; j < 8; ++j) dot += ysum[g * 8 + j] * (float)h[j];
    }
    visual[(size_t)b * SX + x] = dot * INV_N;
  } else {
    #pragma unroll
    for (int i = 0; i < 8; ++i) {
      int e = i * 256 + t;
      int bb = e >> 7, d = e & 127;
      const float* p = out_ws + (size_t)bb * 128 * 128 + d;
      float s = 0.f;
      for (int j = 0; j < 128; ++j) s += p[j * 128];
      out[bb * 128 + d] = s * INV_N;
    }
  }
}

extern "C" void kernel_launch(void* const* d_in, const int* in_sizes, int n_in,
                              void* d_out, int out_size, void* d_ws, size_t ws_size,
                              hipStream_t stream) {
  const float* x = (const float*)d_in[0];   // [B, SX, D]
  const float* y = (const float*)d_in[1];   // [B, SY, D]
  float* visual = (float*)d_out;                      // [B, SX]
  float* out    = (float*)d_out + (size_t)Bn * SX;    // [B, D]

  _Float16* y16  = (_Float16*)d_ws;
  _Float16* x16  = y16 + NE;
  _Float16* xT16 = x16 + NE;
  float* wsf    = (float*)(xT16 + NE);
  float* out_ws = wsf;                      // 2048 waves x 128 = 1 MB
  float* ysump  = wsf + (size_t)2048 * 128; // 512 x 128 = 256 KB

  prep_kernel<<<512, 256, 0, stream>>>(x, y, x16, xT16, y16, ysump);
  attn_kernel<<<512, 256, 0, stream>>>(x16, xT16, y16, out_ws);
  finale_kernel<<<129, 256, 0, stream>>>(x16, ysump, out_ws, visual, out);
}

// Round 6
// 320.005 us; speedup vs baseline: 1.2852x; 1.0659x over previous
//
#include <hip/hip_runtime.h>
#include <math.h>

constexpr int Bn = 16, SY = 2048, SX = 2048, Dd = 128;
constexpr int XT = 64;
constexpr int PIT = 72;   // halfword pitch: 144B = 9x16B, conflict-balanced
constexpr float INV_N = 1.0f / 2048.0f;
constexpr size_t NE = (size_t)Bn * SY * Dd;   // 4,194,304 elements

using half8  = __attribute__((ext_vector_type(8))) _Float16;
using half4  = __attribute__((ext_vector_type(4))) _Float16;
using floatx4 = __attribute__((ext_vector_type(4))) float;

#define DPP_ROR(v, ctrl) __int_as_float(__builtin_amdgcn_update_dpp( \
    __float_as_int(v), __float_as_int(v), (ctrl), 0xf, 0xf, false))

__device__ __forceinline__ float rowmax16(float v) {
  v = fmaxf(v, DPP_ROR(v, 0x121));   // ror 1 within 16-lane row
  v = fmaxf(v, DPP_ROR(v, 0x122));   // ror 2
  v = fmaxf(v, DPP_ROR(v, 0x124));   // ror 4
  v = fmaxf(v, DPP_ROR(v, 0x128));   // ror 8
  return v;                          // all 16 lanes hold the max
}

__device__ __forceinline__ float sel4(const float* a, int q) {
  float r = a[0];
  r = (q == 1) ? a[1] : r;
  r = (q == 2) ? a[2] : r;
  r = (q == 3) ? a[3] : r;
  return r;
}

// grid 1024, 256 thr: block sums 32 consecutive y-rows (global rows blk*32)
// into ysump[blk][128] (fp32 column partial sums).
__global__ void ysum_kernel(const float* __restrict__ y, float* __restrict__ ysump) {
  __shared__ float psum[8][128];
  const int t = threadIdx.x, blk = blockIdx.x;
  const float* ysrc = y + (size_t)blk * 32 * Dd;
  float cp[4] = {0.f, 0.f, 0.f, 0.f};
  #pragma unroll
  for (int it = 0; it < 4; ++it) {
    int tau = it * 256 + t;
    int row = tau >> 5, c4 = tau & 31;
    floatx4 f = *(const floatx4*)(ysrc + row * Dd + 4 * c4);
    cp[0] += f[0]; cp[1] += f[1]; cp[2] += f[2]; cp[3] += f[3];
  }
  *(floatx4*)&psum[t >> 5][(t & 31) * 4] = (floatx4){cp[0], cp[1], cp[2], cp[3]};
  __syncthreads();
  if (t < 128) {
    float s = 0.f;
    #pragma unroll
    for (int i = 0; i < 8; ++i) s += psum[i][t];
    ysump[(size_t)blk * 128 + t] = s;
  }
}

// grid 512, 256 thr: x fp32 -> x16 (row-major fp16) + xT16 (d-major fp16).
__global__ void xprep_kernel(const float* __restrict__ x,
                             _Float16* __restrict__ x16, _Float16* __restrict__ xT16) {
  __shared__ _Float16 lt[128 * PIT];
  const int t = threadIdx.x;
  const int b = blockIdx.x >> 5, rb = blockIdx.x & 31;
  const float* xp = x + ((size_t)b * SX + rb * 64) * Dd;
  _Float16* x16p = x16 + ((size_t)b * SX + rb * 64) * Dd;
  #pragma unroll
  for (int it = 0; it < 8; ++it) {           // 64 rows x 32 float4-cols
    int tau = it * 256 + t;
    int row = tau >> 5, c4 = tau & 31;
    floatx4 f = *(const floatx4*)(xp + row * Dd + 4 * c4);
    half4 h;
    h[0]=(_Float16)f[0]; h[1]=(_Float16)f[1]; h[2]=(_Float16)f[2]; h[3]=(_Float16)f[3];
    *(half4*)(x16p + row * Dd + 4 * c4) = h;
    #pragma unroll
    for (int j = 0; j < 4; ++j) lt[(4 * c4 + j) * PIT + row] = h[j];
  }
  __syncthreads();
  #pragma unroll
  for (int it = 0; it < 4; ++it) {           // 128 d-rows x 8 granules of 16B
    int tau = it * 256 + t;
    int d = tau >> 3, g = tau & 7;
    half8 h = *(const half8*)&lt[d * PIT + g * 8];
    *(half8*)(xT16 + (size_t)(b * Dd + d) * SX + rb * 64 + g * 8) = h;
  }
}

// grid 512 (XCD-swizzled), 512 thr = 8 waves: y-group g = w&3 (16 rows),
// x-chunk = w>>2 (16 of 32 x-tiles). Flash per wave; cross-chunk (m,l) merge
// through LDS at the end; per-block 128-float out partial. No in-loop barriers.
__launch_bounds__(512, 4)
__global__ void attn_kernel(const _Float16* __restrict__ x16, const _Float16* __restrict__ xT16,
                            const float* __restrict__ y, float* __restrict__ out_ws) {
  __shared__ _Float16 Pw[8][16 * PIT];   // per-wave P [m][xcol]
  __shared__ float ml_m[8][16], ml_l[8][16];
  __shared__ float cbuf[8][128];

  const int t = threadIdx.x;
  const int w = t >> 6, lane = t & 63;
  const int n = lane & 15, q = lane >> 4;
  const int g = w & 3, chunk = w >> 2;
  const int xcd = blockIdx.x & 7, kk = blockIdx.x >> 3;
  const int b = (xcd << 1) | (kk & 1);   // pin each batch's ~1MB x-set to one XCD
  const int yblk = kk >> 1;
  const int y0 = yblk * 64;

  // ---- y A-frags straight from fp32 y (8 loads, once) ----
  const float* yrow = y + (size_t)(b * SY + y0 + g * 16 + n) * Dd;
  half8 afrag[4];
  #pragma unroll
  for (int k = 0; k < 4; ++k) {
    floatx4 f0 = *(const floatx4*)(yrow + k * 32 + q * 8);
    floatx4 f1 = *(const floatx4*)(yrow + k * 32 + q * 8 + 4);
    half8 h;
    h[0]=(_Float16)f0[0]; h[1]=(_Float16)f0[1]; h[2]=(_Float16)f0[2]; h[3]=(_Float16)f0[3];
    h[4]=(_Float16)f1[0]; h[5]=(_Float16)f1[1]; h[6]=(_Float16)f1[2]; h[7]=(_Float16)f1[3];
    afrag[k] = h;
  }

  half8 ones;
  #pragma unroll
  for (int j = 0; j < 8; ++j) ones[j] = (_Float16)1.0f;

  float m_r[4];
  floatx4 acc_o[8], lacc;
  #pragma unroll
  for (int r = 0; r < 4; ++r) m_r[r] = -INFINITY;
  #pragma unroll
  for (int d = 0; d < 8; ++d) acc_o[d] = (floatx4){0, 0, 0, 0};
  lacc = (floatx4){0, 0, 0, 0};

  const _Float16* xb  = x16  + (size_t)b * SX * Dd;
  const _Float16* xTb = xT16 + (size_t)b * Dd * SX;
  _Float16* P = Pw[w];

  for (int it = 0; it < 16; ++it) {
    const int tile = chunk * 16 + it;
    const _Float16* xt = xb + (size_t)tile * XT * Dd;

    // ---- S = y @ x^T (16x64) ----
    floatx4 s[4];
    #pragma unroll
    for (int c = 0; c < 4; ++c) s[c] = (floatx4){0, 0, 0, 0};
    #pragma unroll
    for (int k = 0; k < 4; ++k) {
      half8 bf[4];
      #pragma unroll
      for (int c = 0; c < 4; ++c)
        bf[c] = *(const half8*)(xt + (16 * c + n) * Dd + k * 32 + q * 8);
      #pragma unroll
      for (int c = 0; c < 4; ++c)
        s[c] = __builtin_amdgcn_mfma_f32_16x16x32_f16(afrag[k], bf[c], s[c], 0, 0, 0);
    }

    // ---- online softmax (DPP row max, no DS) ----
    float mt[4], al[4];
    #pragma unroll
    for (int r = 0; r < 4; ++r) {
      float mv = fmaxf(fmaxf(s[0][r], s[1][r]), fmaxf(s[2][r], s[3][r]));
      mv = rowmax16(mv);
      mt[r] = fmaxf(m_r[r], mv);
      al[r] = __expf(m_r[r] - mt[r]);   // 0 on first tile
      m_r[r] = mt[r];
    }
    #pragma unroll
    for (int r = 0; r < 4; ++r) {
      #pragma unroll
      for (int c = 0; c < 4; ++c)
        P[(4 * q + r) * PIT + 16 * c + n] = (_Float16)__expf(s[c][r] - mt[r]);
      lacc[r] *= al[r];
      #pragma unroll
      for (int d = 0; d < 8; ++d) acc_o[d][r] *= al[r];
    }

    // ---- PV + l via MFMA-with-ones (same-wave LDS RAW, no barrier) ----
    const _Float16* xT = xTb + tile * XT;
    #pragma unroll
    for (int k2 = 0; k2 < 2; ++k2) {
      half8 pf = *(const half8*)&P[n * PIT + k2 * 32 + q * 8];
      lacc = __builtin_amdgcn_mfma_f32_16x16x32_f16(pf, ones, lacc, 0, 0, 0);
      #pragma unroll
      for (int d = 0; d < 8; ++d) {
        half8 xf = *(const half8*)(xT + (size_t)(16 * d + n) * SX + k2 * 32 + q * 8);
        acc_o[d] = __builtin_amdgcn_mfma_f32_16x16x32_f16(pf, xf, acc_o[d], 0, 0, 0);
      }
    }
  }

  // ---- cross-chunk merge: exchange (m, l) only ----
  if (n == 0) {
    #pragma unroll
    for (int r = 0; r < 4; ++r) {
      ml_m[w][4 * q + r] = m_r[r];
      ml_l[w][4 * q + r] = lacc[r];   // cols identical (B = ones)
    }
  }
  __syncthreads();
  const int p = w ^ 4;   // partner: same y-group, other chunk
  float scale[4];
  #pragma unroll
  for (int r = 0; r < 4; ++r) {
    float mp = ml_m[p][4 * q + r], lp = ml_l[p][4 * q + r];
    float M = fmaxf(m_r[r], mp);
    float f = __expf(m_r[r] - M);
    float l_tot = f * lacc[r] + __expf(mp - M) * lp;
    scale[r] = f / l_tot;
  }

  // ---- fold own O into 128-float contribution (in-register) ----
  float ps[8];
  #pragma unroll
  for (int d = 0; d < 8; ++d) {
    float s = acc_o[d][0] * scale[0] + acc_o[d][1] * scale[1] +
              acc_o[d][2] * scale[2] + acc_o[d][3] * scale[3];
    s += __shfl_xor(s, 16);
    s += __shfl_xor(s, 32);
    ps[d] = s;   // 16-row sum for col 16d+n, replicated
  }
  cbuf[w][16 * q + n]      = sel4(ps, q);       // d 0..63
  cbuf[w][64 + 16 * q + n] = sel4(ps + 4, q);   // d 64..127
  __syncthreads();
  if (t < 128) {
    float s = 0.f;
    #pragma unroll
    for (int i = 0; i < 8; ++i) s += cbuf[i][t];
    out_ws[(size_t)(b * 32 + yblk) * 128 + t] = s;
  }
}

// grid 129, 256 thr. Blocks 0..127: visual[b, x0..x0+255] = (ysum . x)/2048.
// Block 128: out[b][d] = mean over 32 block-partials.
__global__ void finale_kernel(const _Float16* __restrict__ x16, const float* __restrict__ ysump,
                              const float* __restrict__ out_ws,
                              float* __restrict__ visual, float* __restrict__ out) {
  const int t = threadIdx.x, blk = blockIdx.x;
  if (blk < 128) {
    __shared__ float ysum[128];
    const int b = blk >> 3, x0 = (blk & 7) * 256;
    if (t < 128) {
      float s = 0.f;
      #pragma unroll
      for (int j = 0; j < 64; ++j) s += ysump[(size_t)(b * 64 + j) * 128 + t];
      ysum[t] = s;
    }
    __syncthreads();
    const int x = x0 + t;
    const _Float16* xr = x16 + ((size_t)b * SX + x) * Dd;
    float dot = 0.f;
    #pragma unroll
    for (int g = 0; g < 16; ++g) {
      half8 h = *(const half8*)(xr + g * 8);
      #pragma unroll
      for (int j = 0; j < 8; ++j) dot += ysum[g * 8 + j] * (float)h[j];
    }
    visual[(size_t)b * SX + x] = dot * INV_N;
  } else {
    #pragma unroll
    for (int i = 0; i < 8; ++i) {
      int e = i * 256 + t;
      int bb = e >> 7, d = e & 127;
      float s = 0.f;
      for (int j = 0; j < 32; ++j) s += out_ws[(size_t)(bb * 32 + j) * 128 + d];
      out[bb * 128 + d] = s * INV_N;
    }
  }
}

extern "C" void kernel_launch(void* const* d_in, const int* in_sizes, int n_in,
                              void* d_out, int out_size, void* d_ws, size_t ws_size,
                              hipStream_t stream) {
  const float* x = (const float*)d_in[0];   // [B, SX, D]
  const float* y = (const float*)d_in[1];   // [B, SY, D]
  float* visual = (float*)d_out;                      // [B, SX]
  float* out    = (float*)d_out + (size_t)Bn * SX;    // [B, D]

  _Float16* x16  = (_Float16*)d_ws;
  _Float16* xT16 = x16 + NE;
  float* wsf    = (float*)(xT16 + NE);
  float* out_ws = wsf;                       // 512 blocks x 128 = 256 KB
  float* ysump  = wsf + (size_t)512 * 128;   // 1024 x 128 = 512 KB

  ysum_kernel<<<1024, 256, 0, stream>>>(y, ysump);
  xprep_kernel<<<512, 256, 0, stream>>>(x, x16, xT16);
  attn_kernel<<<512, 512, 0, stream>>>(x16, xT16, y, out_ws);
  finale_kernel<<<129, 256, 0, stream>>>(x16, ysump, out_ws, visual, out);
}

// Round 7
// 150.940 us; speedup vs baseline: 2.7247x; 2.1201x over previous
//
#include <hip/hip_runtime.h>
#include <math.h>

constexpr int Bn = 16, SY = 2048, SX = 2048, Dd = 128;
constexpr int XT = 64;
constexpr int NXT = SX / XT;   // 32
constexpr int PIT = 72;        // halfword pitch for P: 144B = 9x16B
constexpr float INV_N = 1.0f / 2048.0f;
constexpr size_t NE = (size_t)Bn * SY * Dd;

using half8  = __attribute__((ext_vector_type(8))) _Float16;
using half4  = __attribute__((ext_vector_type(4))) _Float16;
using floatx4 = __attribute__((ext_vector_type(4))) float;

#define DPP_ROR(v, ctrl) __int_as_float(__builtin_amdgcn_update_dpp( \
    __float_as_int(v), __float_as_int(v), (ctrl), 0xf, 0xf, false))

__device__ __forceinline__ float rowmax16(float v) {
  v = fmaxf(v, DPP_ROR(v, 0x121));
  v = fmaxf(v, DPP_ROR(v, 0x122));
  v = fmaxf(v, DPP_ROR(v, 0x124));
  v = fmaxf(v, DPP_ROR(v, 0x128));
  return v;   // replicated across the 16-lane row
}
__device__ __forceinline__ float rowsum16(float v) {
  v += DPP_ROR(v, 0x121);
  v += DPP_ROR(v, 0x122);
  v += DPP_ROR(v, 0x124);
  v += DPP_ROR(v, 0x128);
  return v;
}

__device__ __forceinline__ float sel4(const float* a, int q) {
  float r = a[0];
  r = (q == 1) ? a[1] : r;
  r = (q == 2) ? a[2] : r;
  r = (q == 3) ? a[3] : r;
  return r;
}

// async global->LDS, 16B per lane; LDS dst = uniform base + lane*16
__device__ __forceinline__ void gld_lds16(const _Float16* g, _Float16* l) {
  __builtin_amdgcn_global_load_lds(
      (const __attribute__((address_space(1))) void*)g,
      (__attribute__((address_space(3))) void*)l, 16, 0, 0);
}

// grid 512, 256 thr: x fp32 -> x16 (row-major fp16) + xT16 (d-major fp16).
__global__ void xprep_kernel(const float* __restrict__ x,
                             _Float16* __restrict__ x16, _Float16* __restrict__ xT16) {
  __shared__ _Float16 lt[128 * PIT];
  const int t = threadIdx.x;
  const int b = blockIdx.x >> 5, rb = blockIdx.x & 31;
  const float* xp = x + ((size_t)b * SX + rb * 64) * Dd;
  _Float16* x16p = x16 + ((size_t)b * SX + rb * 64) * Dd;
  #pragma unroll
  for (int it = 0; it < 8; ++it) {
    int tau = it * 256 + t;
    int row = tau >> 5, c4 = tau & 31;
    floatx4 f = *(const floatx4*)(xp + row * Dd + 4 * c4);
    half4 h;
    h[0]=(_Float16)f[0]; h[1]=(_Float16)f[1]; h[2]=(_Float16)f[2]; h[3]=(_Float16)f[3];
    *(half4*)(x16p + row * Dd + 4 * c4) = h;
    #pragma unroll
    for (int j = 0; j < 4; ++j) lt[(4 * c4 + j) * PIT + row] = h[j];
  }
  __syncthreads();
  #pragma unroll
  for (int it = 0; it < 4; ++it) {
    int tau = it * 256 + t;
    int d = tau >> 3, g = tau & 7;
    half8 h = *(const half8*)&lt[d * PIT + g * 8];
    *(half8*)(xT16 + (size_t)(b * Dd + d) * SX + rb * 64 + g * 8) = h;
  }
}

// grid 512 (XCD-swizzled): (b, yblk of 64 y-rows), 4 waves = 4 y-groups of 16.
// Double-buffered LDS x-tiles staged via global_load_lds (source-swizzled so
// ds_read_b128 fragments are <=2-way bank aliased). One barrier per x-tile.
__launch_bounds__(256, 2)
__global__ void attn_kernel(const _Float16* __restrict__ x16, const _Float16* __restrict__ xT16,
                            const float* __restrict__ y,
                            float* __restrict__ out_ws, float* __restrict__ ysump) {
  __shared__ _Float16 xrm[2][64 * 128];    // x tile row-major [xrow][d], granule-swizzled
  __shared__ _Float16 xtp[2][128 * 64];    // x tile d-major [d][xcol], granule-swizzled
  __shared__ _Float16 Pw[4][16 * PIT];     // per-wave P [m][xcol], padded
  __shared__ float ysw[4][128];            // per-wave y column partial sums
  __shared__ float cbuf[4][128];           // epilogue out partials

  const int t = threadIdx.x;
  const int w = t >> 6, lane = t & 63;
  const int n = lane & 15, q = lane >> 4;
  const int xcd = blockIdx.x & 7, kk = blockIdx.x >> 3;
  const int b = (xcd << 1) | (kk & 1);
  const int yblk = kk >> 1;
  const int y0 = yblk * 64;

  // ---- y A-frags from fp32 y + fold column sums (for visual) ----
  const float* yrow = y + (size_t)(b * SY + y0 + w * 16 + n) * Dd;
  half8 afrag[4];
  {
    float yv[4][8];
    #pragma unroll
    for (int k = 0; k < 4; ++k) {
      floatx4 f0 = *(const floatx4*)(yrow + k * 32 + q * 8);
      floatx4 f1 = *(const floatx4*)(yrow + k * 32 + q * 8 + 4);
      half8 h;
      h[0]=(_Float16)f0[0]; h[1]=(_Float16)f0[1]; h[2]=(_Float16)f0[2]; h[3]=(_Float16)f0[3];
      h[4]=(_Float16)f1[0]; h[5]=(_Float16)f1[1]; h[6]=(_Float16)f1[2]; h[7]=(_Float16)f1[3];
      afrag[k] = h;
      #pragma unroll
      for (int j = 0; j < 4; ++j) { yv[k][j] = f0[j]; yv[k][4 + j] = f1[j]; }
    }
    #pragma unroll
    for (int k = 0; k < 4; ++k)
      #pragma unroll
      for (int j = 0; j < 8; ++j) {
        float s = rowsum16(yv[k][j]);   // sum over this wave's 16 y-rows
        if (n == 0) ysw[w][k * 32 + q * 8 + j] = s;
      }
  }

  half8 ones;
  #pragma unroll
  for (int j = 0; j < 8; ++j) ones[j] = (_Float16)1.0f;

  float m_r[4];
  floatx4 acc_o[8], lacc;
  #pragma unroll
  for (int r = 0; r < 4; ++r) m_r[r] = -INFINITY;
  #pragma unroll
  for (int d = 0; d < 8; ++d) acc_o[d] = (floatx4){0, 0, 0, 0};
  lacc = (floatx4){0, 0, 0, 0};

  const _Float16* xb  = x16  + (size_t)b * SX * Dd;
  const _Float16* xTb = xT16 + (size_t)b * Dd * SX;
  _Float16* P = Pw[w];

  // ---- per-lane staging maps (wave w issues instrs i = 4w..4w+3 per region) ----
  // region granule G = i*64 + lane; LDS hw offset = G*8 (unpadded, required).
  int l_off[4], off_rm[4], off_xt[4];
  #pragma unroll
  for (int ii = 0; ii < 4; ++ii) {
    int G = (w * 4 + ii) * 64 + lane;
    l_off[ii] = G * 8;
    { int row = G >> 4, gs = G & 15, g = (gs - row) & 15;   // xrm: 64 rows x 16 granules
      off_rm[ii] = row * 128 + g * 8; }
    { int row = G >> 3, gs = G & 7, g = (gs - row) & 7;     // xtp: 128 rows x 8 granules
      off_xt[ii] = row * SX + g * 8; }
  }

  // stage tile 0 into buffer 0
  #pragma unroll
  for (int ii = 0; ii < 4; ++ii) {
    gld_lds16(xb + off_rm[ii], &xrm[0][l_off[ii]]);
    gld_lds16(xTb + off_xt[ii], &xtp[0][l_off[ii]]);
  }
  __syncthreads();

  for (int it = 0; it < NXT; ++it) {
    const int cur = it & 1;

    // ---- prefetch tile it+1 into the other buffer ----
    if (it + 1 < NXT) {
      const _Float16* xsrc  = xb + (size_t)(it + 1) * XT * Dd;
      const _Float16* xTsrc = xTb + (it + 1) * XT;
      #pragma unroll
      for (int ii = 0; ii < 4; ++ii) {
        gld_lds16(xsrc + off_rm[ii], &xrm[cur ^ 1][l_off[ii]]);
        gld_lds16(xTsrc + off_xt[ii], &xtp[cur ^ 1][l_off[ii]]);
      }
    }

    // ---- S = y @ x^T (16x64 per wave), B-frags via swizzled ds_read_b128 ----
    floatx4 s[4];
    #pragma unroll
    for (int c = 0; c < 4; ++c) s[c] = (floatx4){0, 0, 0, 0};
    #pragma unroll
    for (int k = 0; k < 4; ++k) {
      half8 bf[4];
      #pragma unroll
      for (int c = 0; c < 4; ++c) {
        int row = 16 * c + n;
        int sw = (k * 4 + q + row) & 15;
        bf[c] = *(const half8*)&xrm[cur][row * 128 + sw * 8];
      }
      #pragma unroll
      for (int c = 0; c < 4; ++c)
        s[c] = __builtin_amdgcn_mfma_f32_16x16x32_f16(afrag[k], bf[c], s[c], 0, 0, 0);
    }

    // ---- online softmax (DPP row max) ----
    float mt[4], al[4];
    #pragma unroll
    for (int r = 0; r < 4; ++r) {
      float mv = fmaxf(fmaxf(s[0][r], s[1][r]), fmaxf(s[2][r], s[3][r]));
      mv = rowmax16(mv);
      mt[r] = fmaxf(m_r[r], mv);
      al[r] = __expf(m_r[r] - mt[r]);
      m_r[r] = mt[r];
    }
    #pragma unroll
    for (int r = 0; r < 4; ++r) {
      #pragma unroll
      for (int c = 0; c < 4; ++c)
        P[(4 * q + r) * PIT + 16 * c + n] = (_Float16)__expf(s[c][r] - mt[r]);
      lacc[r] *= al[r];
      #pragma unroll
      for (int d = 0; d < 8; ++d) acc_o[d][r] *= al[r];
    }

    // ---- PV + l via MFMA-with-ones (same-wave LDS RAW) ----
    #pragma unroll
    for (int k2 = 0; k2 < 2; ++k2) {
      half8 pf = *(const half8*)&P[n * PIT + k2 * 32 + q * 8];
      lacc = __builtin_amdgcn_mfma_f32_16x16x32_f16(pf, ones, lacc, 0, 0, 0);
      #pragma unroll
      for (int d = 0; d < 8; ++d) {
        int row = 16 * d + n;
        int sw = (k2 * 4 + q + row) & 7;
        half8 xf = *(const half8*)&xtp[cur][row * 64 + sw * 8];
        acc_o[d] = __builtin_amdgcn_mfma_f32_16x16x32_f16(pf, xf, acc_o[d], 0, 0, 0);
      }
    }

    __syncthreads();   // readers of cur done + prefetch (vmcnt drained) visible
  }

  // ---- epilogue: fold O/l into 128-float contribution ----
  float inv_l[4];
  #pragma unroll
  for (int r = 0; r < 4; ++r) inv_l[r] = 1.f / lacc[r];
  float ps[8];
  #pragma unroll
  for (int d = 0; d < 8; ++d) {
    float s = acc_o[d][0] * inv_l[0] + acc_o[d][1] * inv_l[1] +
              acc_o[d][2] * inv_l[2] + acc_o[d][3] * inv_l[3];
    s += __shfl_xor(s, 16);
    s += __shfl_xor(s, 32);
    ps[d] = s;
  }
  cbuf[w][16 * q + n]      = sel4(ps, q);
  cbuf[w][64 + 16 * q + n] = sel4(ps + 4, q);
  __syncthreads();
  if (t < 128) {
    float s = 0.f, yp = 0.f;
    #pragma unroll
    for (int i = 0; i < 4; ++i) { s += cbuf[i][t]; yp += ysw[i][t]; }
    out_ws[(size_t)(b * 32 + yblk) * 128 + t] = s;
    ysump[(size_t)(b * 32 + yblk) * 128 + t] = yp;
  }
}

// grid 129, 256 thr. Blocks 0..127: visual[b, x0..x0+255] = (ysum . x)/2048.
// Block 128: out[b][d] = mean over 32 block-partials.
__global__ void finale_kernel(const _Float16* __restrict__ x16, const float* __restrict__ ysump,
                              const float* __restrict__ out_ws,
                              float* __restrict__ visual, float* __restrict__ out) {
  const int t = threadIdx.x, blk = blockIdx.x;
  if (blk < 128) {
    __shared__ float ysum[128];
    const int b = blk >> 3, x0 = (blk & 7) * 256;
    if (t < 128) {
      float s = 0.f;
      #pragma unroll
      for (int j = 0; j < 32; ++j) s += ysump[(size_t)(b * 32 + j) * 128 + t];
      ysum[t] = s;
    }
    __syncthreads();
    const int x = x0 + t;
    const _Float16* xr = x16 + ((size_t)b * SX + x) * Dd;
    float dot = 0.f;
    #pragma unroll
    for (int g = 0; g < 16; ++g) {
      half8 h = *(const half8*)(xr + g * 8);
      #pragma unroll
      for (int j = 0; j < 8; ++j) dot += ysum[g * 8 + j] * (float)h[j];
    }
    visual[(size_t)b * SX + x] = dot * INV_N;
  } else {
    #pragma unroll
    for (int i = 0; i < 8; ++i) {
      int e = i * 256 + t;
      int bb = e >> 7, d = e & 127;
      float s = 0.f;
      for (int j = 0; j < 32; ++j) s += out_ws[(size_t)(bb * 32 + j) * 128 + d];
      out[bb * 128 + d] = s * INV_N;
    }
  }
}

extern "C" void kernel_launch(void* const* d_in, const int* in_sizes, int n_in,
                              void* d_out, int out_size, void* d_ws, size_t ws_size,
                              hipStream_t stream) {
  const float* x = (const float*)d_in[0];   // [B, SX, D]
  const float* y = (const float*)d_in[1];   // [B, SY, D]
  float* visual = (float*)d_out;                      // [B, SX]
  float* out    = (float*)d_out + (size_t)Bn * SX;    // [B, D]

  _Float16* x16  = (_Float16*)d_ws;
  _Float16* xT16 = x16 + NE;
  float* wsf    = (float*)(xT16 + NE);
  float* out_ws = wsf;                       // 512 x 128 = 256 KB
  float* ysump  = wsf + (size_t)512 * 128;   // 512 x 128 = 256 KB

  xprep_kernel<<<512, 256, 0, stream>>>(x, x16, xT16);
  attn_kernel<<<512, 256, 0, stream>>>(x16, xT16, y, out_ws, ysump);
  finale_kernel<<<129, 256, 0, stream>>>(x16, ysump, out_ws, visual, out);
}